// Round 1
// baseline (798.845 us; speedup 1.0000x reference)
//
#include <hip/hip_runtime.h>
#include <hip/hip_bf16.h>

#define Bn 8
#define Cn 64
#define Hh 128
#define Wi 128
#define Np 16384      // H*W
#define Sc 32         // clusters
#define On 64         // output channels
#define Dd 576        // C*9
#define KM_ITERS 8
#define NB 64         // kmeans blocks per batch (256 px each)
#define NBP 32        // centp blocks per batch (512 px each)

typedef float f32x4 __attribute__((ext_vector_type(4)));
typedef __bf16 bf16x8 __attribute__((ext_vector_type(8)));
typedef short short8v __attribute__((ext_vector_type(8)));

// ---------------- transpose x[b][c][n] -> feat_t[b][n][c] ----------------
__global__ __launch_bounds__(256) void transpose_k(const float* __restrict__ x,
                                                   float* __restrict__ feat_t) {
    __shared__ float tile[64][65];
    int b = blockIdx.y, n0 = blockIdx.x * 64, t = threadIdx.x;
    int j = t & 63, c0 = (t >> 6) * 16;
    for (int cc = 0; cc < 16; ++cc) {
        int c = c0 + cc;
        tile[c][j] = x[((size_t)b * Cn + c) * Np + n0 + j];
    }
    __syncthreads();
    int cr = t & 63, j0 = (t >> 6) * 16;
    for (int jj = 0; jj < 16; ++jj) {
        int j2 = j0 + jj;
        feat_t[((size_t)b * Np + n0 + j2) * Cn + cr] = tile[cr][j2];
    }
}

// ---------------- centroid init: cent[b][s][:] = feat[b][s*512][:] ----------------
__global__ __launch_bounds__(64) void init_cent_k(const float* __restrict__ x,
                                                  float* __restrict__ cent,
                                                  float* __restrict__ cnorm) {
    int b = blockIdx.y, s = blockIdx.x, c = threadIdx.x;
    int n = s * (Np / Sc);
    float v = x[((size_t)b * Cn + c) * Np + n];
    cent[(b * Sc + s) * Cn + c] = v;
    float sq = v * v;
    #pragma unroll
    for (int off = 32; off >= 1; off >>= 1) sq += __shfl_down(sq, off);
    if (c == 0) cnorm[b * Sc + s] = sq;
}

// ---------------- w2 -> bf16 (already [o][c*9+k] layout) ----------------
__global__ __launch_bounds__(256) void w2bf_k(const float* __restrict__ w2,
                                              __bf16* __restrict__ w2bf) {
    int i = blockIdx.x * 256 + threadIdx.x;
    if (i < On * Dd) w2bf[i] = (__bf16)w2[i];
}

// ---------------- assignment helper (f32, strict-< argmin) ----------------
__device__ __forceinline__ int assign_pixel(const float* __restrict__ x,
                                            const float cent_s[Sc][Cn],
                                            const float* cnorm_s, int b, int n) {
    float acc[Sc];
    #pragma unroll
    for (int s = 0; s < Sc; ++s) acc[s] = 0.f;
    #pragma unroll 4
    for (int c = 0; c < Cn; ++c) {
        float f = x[((size_t)b * Cn + c) * Np + n];
        #pragma unroll
        for (int s = 0; s < Sc; ++s) acc[s] = fmaf(f, cent_s[s][c], acc[s]);
    }
    int best = 0;
    float bd = cnorm_s[0] - 2.f * acc[0];
    #pragma unroll
    for (int s = 1; s < Sc; ++s) {
        float d = cnorm_s[s] - 2.f * acc[s];
        if (d < bd) { bd = d; best = s; }
    }
    return best;
}

// ---------------- one Lloyd iteration: assign + deterministic partial sums ----------------
__global__ __launch_bounds__(256) void kmeans_iter_k(const float* __restrict__ x,
                                                     const float* __restrict__ feat_t,
                                                     const float* __restrict__ cent,
                                                     const float* __restrict__ cnorm,
                                                     int* __restrict__ idxg,
                                                     float* __restrict__ gpart) {
    __shared__ float cent_s[Sc][Cn];
    __shared__ float cnorm_s[Sc];
    __shared__ int   idx_s[256];
    __shared__ float part[4][Sc][Cn + 1];
    int b = blockIdx.y, n0 = blockIdx.x * 256, t = threadIdx.x;

    for (int i = t; i < Sc * Cn; i += 256) ((float*)cent_s)[i] = cent[b * Sc * Cn + i];
    if (t < Sc) cnorm_s[t] = cnorm[b * Sc + t];
    for (int i = t; i < 4 * Sc * (Cn + 1); i += 256) ((float*)part)[i] = 0.f;
    __syncthreads();

    int n = n0 + t;
    int best = assign_pixel(x, cent_s, cnorm_s, b, n);
    idx_s[t] = best;
    idxg[b * Np + n] = best;
    __syncthreads();

    // per-wave deterministic accumulation (serial over 64 pixels, lane = channel)
    int w = t >> 6, c = t & 63;
    for (int p = 0; p < 64; ++p) {
        int pp = w * 64 + p;
        int s = idx_s[pp];
        float v = feat_t[((size_t)b * Np + n0 + pp) * Cn + c];
        part[w][s][c] += v;
        if (c == 0) part[w][s][Cn] += 1.f;
    }
    __syncthreads();

    const int plane = Sc * (Cn + 1);
    float* gp = gpart + (size_t)(b * NB + blockIdx.x) * plane;
    const float* p0 = (const float*)part;
    for (int i = t; i < plane; i += 256)
        gp[i] = p0[i] + p0[plane + i] + p0[2 * plane + i] + p0[3 * plane + i];
}

// ---------------- reduce partials -> new centroids ----------------
__global__ __launch_bounds__(256) void update_cent_k(const float* __restrict__ gpart,
                                                     float* __restrict__ cent,
                                                     float* __restrict__ cnorm) {
    int t = threadIdx.x;
    int pair = blockIdx.x * 4 + (t >> 6);
    int b = pair >> 5, s = pair & 31, c = t & 63;
    float sum = 0.f, cnt = 0.f;
    for (int blk = 0; blk < NB; ++blk) {
        const float* g = gpart + ((size_t)(b * NB + blk) * Sc + s) * (Cn + 1);
        sum += g[c];
        cnt += g[Cn];
    }
    float ce = sum / fmaxf(cnt, 1.f);
    cent[(b * Sc + s) * Cn + c] = ce;
    float sq = ce * ce;
    #pragma unroll
    for (int off = 32; off >= 1; off >>= 1) sq += __shfl_down(sq, off);
    if (c == 0) cnorm[b * Sc + s] = sq;
}

// ---------------- final assignment (writes idx int + float output chunk) ----------------
__global__ __launch_bounds__(256) void assign_final_k(const float* __restrict__ x,
                                                      const float* __restrict__ cent,
                                                      const float* __restrict__ cnorm,
                                                      int* __restrict__ idxg,
                                                      float* __restrict__ out_idx) {
    __shared__ float cent_s[Sc][Cn];
    __shared__ float cnorm_s[Sc];
    int b = blockIdx.y, n0 = blockIdx.x * 256, t = threadIdx.x;
    for (int i = t; i < Sc * Cn; i += 256) ((float*)cent_s)[i] = cent[b * Sc * Cn + i];
    if (t < Sc) cnorm_s[t] = cnorm[b * Sc + t];
    __syncthreads();
    int n = n0 + t;
    int best = assign_pixel(x, cent_s, cnorm_s, b, n);
    idxg[b * Np + n] = best;
    out_idx[b * Np + n] = (float)best;
}

// ---------------- per-cluster patch-sum partials (deterministic) ----------------
__global__ __launch_bounds__(576) void centp_partial_k(const float* __restrict__ feat_t,
                                                       const int* __restrict__ idxg,
                                                       float* __restrict__ gpartp) {
    __shared__ float part[Sc][Dd + 1];
    __shared__ int idx_s[512];
    int b = blockIdx.y, n0 = blockIdx.x * 512, t = threadIdx.x;
    for (int i = t; i < Sc * (Dd + 1); i += 576) ((float*)part)[i] = 0.f;
    if (t < 512) idx_s[t] = idxg[b * Np + n0 + t];
    __syncthreads();

    int k = t >> 6, c = t & 63;
    int dh = k / 3 - 1, dw = k % 3 - 1;
    int dcol = c * 9 + k;
    for (int p = 0; p < 512; ++p) {
        int s = idx_s[p];
        int n = n0 + p;
        int h = (n >> 7) + dh, w = (n & 127) + dw;
        float v = 0.f;
        if (((unsigned)h < 128u) && ((unsigned)w < 128u))
            v = feat_t[((size_t)b * Np + (h << 7) + w) * Cn + c];
        part[s][dcol] += v;
        if (t == 0) part[s][Dd] += 1.f;
    }
    __syncthreads();
    float* gp = gpartp + (size_t)(b * NBP + blockIdx.x) * Sc * (Dd + 1);
    for (int i = t; i < Sc * (Dd + 1); i += 576) gp[i] = ((float*)part)[i];
}

// ---------------- reduce patch partials -> cluster mean patch -> softmax attention ----------------
__global__ __launch_bounds__(576) void centp_att_k(const float* __restrict__ gpartp,
                                                   const float* __restrict__ kg_w,
                                                   const float* __restrict__ kg_b,
                                                   float* __restrict__ attb) {
    __shared__ float cp_s[Dd];
    __shared__ float cnt_sh;
    __shared__ float logit[9];
    int b = blockIdx.y, s = blockIdx.x, t = threadIdx.x;
    float sum = 0.f;
    for (int blk = 0; blk < NBP; ++blk)
        sum += gpartp[((size_t)(b * NBP + blk) * Sc + s) * (Dd + 1) + t];
    if (t == 0) {
        float cnt = 0.f;
        for (int blk = 0; blk < NBP; ++blk)
            cnt += gpartp[((size_t)(b * NBP + blk) * Sc + s) * (Dd + 1) + Dd];
        cnt_sh = fmaxf(cnt, 1.f);
    }
    __syncthreads();
    cp_s[t] = sum / cnt_sh;
    __syncthreads();

    int j = t >> 6, l = t & 63;
    float pr = 0.f;
    #pragma unroll
    for (int u = 0; u < 9; ++u)
        pr = fmaf(cp_s[l + 64 * u], kg_w[j * Dd + l + 64 * u], pr);
    #pragma unroll
    for (int off = 32; off >= 1; off >>= 1) pr += __shfl_down(pr, off);
    if (l == 0) logit[j] = pr + kg_b[j];
    __syncthreads();
    if (t == 0) {
        float mx = logit[0];
        #pragma unroll
        for (int jj = 1; jj < 9; ++jj) mx = fmaxf(mx, logit[jj]);
        float e[9], sm = 0.f;
        #pragma unroll
        for (int jj = 0; jj < 9; ++jj) { e[jj] = expf(logit[jj] - mx); sm += e[jj]; }
        #pragma unroll
        for (int jj = 0; jj < 9; ++jj) attb[(b * Sc + s) * 9 + jj] = e[jj] / sm * 9.f;
    }
}

// ---------------- final: y = (patch*att) @ w2^T via bf16 MFMA, out = x + y + b2 ----------------
__global__ __launch_bounds__(256) void final_out_k(const float* __restrict__ x,
                                                   const float* __restrict__ feat_t,
                                                   const int* __restrict__ idxg,
                                                   const float* __restrict__ attb,
                                                   const __bf16* __restrict__ w2bf,
                                                   const float* __restrict__ b2,
                                                   float* __restrict__ out) {
    __shared__ __bf16 pm[64][Dd];    // A tile: 64 pixels x 576 (XOR-swizzled)
    __shared__ __bf16 w2l[64][Dd];   // B tile: 64 outs  x 576 (XOR-swizzled)
    __shared__ float apix[64][12];
    int b = blockIdx.y, n0 = blockIdx.x * 64, t = threadIdx.x;

    // stage w2 (bf16) with per-row chunk swizzle
    for (int i = t; i < 64 * 72; i += 256) {
        int row = i / 72, ch = i % 72;
        int chS = ch ^ (row & 7);
        *(short8v*)&w2l[row][chS * 8] = *(const short8v*)&w2bf[row * Dd + ch * 8];
    }
    // per-pixel attention gather
    if (t < 64) {
        int s = idxg[b * Np + n0 + t];
        const float* ap = attb + (b * Sc + s) * 9;
        #pragma unroll
        for (int k = 0; k < 9; ++k) apix[t][k] = ap[k];
    }
    __syncthreads();

    // build pm = patch * att (bf16), swizzled
    int pix4 = t >> 4;
    int cq = t & 15, c0 = cq * 4;
    #pragma unroll
    for (int k = 0; k < 9; ++k) {
        int dh = k / 3 - 1, dw = k % 3 - 1;
        for (int g = 0; g < 4; ++g) {
            int pix = g * 16 + pix4;
            int n = n0 + pix;
            int h = (n >> 7) + dh, w = (n & 127) + dw;
            f32x4 v = {0.f, 0.f, 0.f, 0.f};
            if (((unsigned)h < 128u) && ((unsigned)w < 128u))
                v = *(const f32x4*)&feat_t[((size_t)b * Np + (h << 7) + w) * Cn + c0];
            float a = apix[pix][k];
            int sw = (pix & 7) << 3;
            pm[pix][(((c0 + 0) * 9 + k)) ^ sw] = (__bf16)(v.x * a);
            pm[pix][(((c0 + 1) * 9 + k)) ^ sw] = (__bf16)(v.y * a);
            pm[pix][(((c0 + 2) * 9 + k)) ^ sw] = (__bf16)(v.z * a);
            pm[pix][(((c0 + 3) * 9 + k)) ^ sw] = (__bf16)(v.w * a);
        }
    }
    __syncthreads();

    // MFMA: each wave computes 16 pixels x 64 outs
    int wv = t >> 6, lane = t & 63;
    int arow = lane & 15, kg = lane >> 4;
    int mrow = wv * 16 + arow;
    int sw = (arow & 7) << 3;   // (mrow&7)==(arow&7) since wv*16 ≡ 0 mod 8
    f32x4 acc[4];
    #pragma unroll
    for (int nt = 0; nt < 4; ++nt) acc[nt] = (f32x4){0.f, 0.f, 0.f, 0.f};
    for (int kk = 0; kk < 18; ++kk) {
        int koS = (kk * 32 + kg * 8) ^ sw;
        bf16x8 av = *(const bf16x8*)&pm[mrow][koS];
        #pragma unroll
        for (int nt = 0; nt < 4; ++nt) {
            bf16x8 bv = *(const bf16x8*)&w2l[nt * 16 + arow][koS];
            acc[nt] = __builtin_amdgcn_mfma_f32_16x16x32_bf16(av, bv, acc[nt], 0, 0, 0);
        }
    }
    __syncthreads();   // all MFMA done before pm is reused as trans

    float (*trans)[65] = (float (*)[65])pm;
    #pragma unroll
    for (int nt = 0; nt < 4; ++nt) {
        #pragma unroll
        for (int r = 0; r < 4; ++r) {
            int pixl = wv * 16 + kg * 4 + r;   // C row = (lane>>4)*4 + r
            int o = nt * 16 + arow;            // C col = lane&15
            trans[o][pixl] = acc[nt][r];
        }
    }
    __syncthreads();

    for (int i = t; i < 4096; i += 256) {
        int o = i >> 6, pix = i & 63;
        size_t gi = ((size_t)b * On + o) * Np + n0 + pix;
        out[gi] = x[gi] + trans[o][pix] + b2[o];
    }
}

extern "C" void kernel_launch(void* const* d_in, const int* in_sizes, int n_in,
                              void* d_out, int out_size, void* d_ws, size_t ws_size,
                              hipStream_t stream) {
    (void)in_sizes; (void)n_in; (void)out_size; (void)ws_size;
    const float* x    = (const float*)d_in[0];
    const float* kg_w = (const float*)d_in[5];
    const float* kg_b = (const float*)d_in[6];
    const float* w2   = (const float*)d_in[7];
    const float* b2   = (const float*)d_in[8];
    float* out = (float*)d_out;

    float* ws     = (float*)d_ws;
    float* feat_t = ws;                                       // 8,388,608
    float* cent   = feat_t + (size_t)Bn * Np * Cn;            // 16,384
    float* cnorm  = cent + Bn * Sc * Cn;                      // 256
    int*   idxg   = (int*)(cnorm + Bn * Sc);                  // 131,072
    float* gpart  = (float*)(idxg + Bn * Np);                 // 1,064,960
    float* gpartp = gpart + (size_t)Bn * NB * Sc * (Cn + 1);  // 4,727,808
    float* attb   = gpartp + (size_t)Bn * NBP * Sc * (Dd + 1);// 2,304
    __bf16* w2bf  = (__bf16*)(attb + Bn * Sc * 9);            // 36,864 bf16

    transpose_k<<<dim3(Np / 64, Bn), 256, 0, stream>>>(x, feat_t);
    init_cent_k<<<dim3(Sc, Bn), 64, 0, stream>>>(x, cent, cnorm);
    w2bf_k<<<(On * Dd) / 256, 256, 0, stream>>>(w2, w2bf);

    for (int it = 0; it < KM_ITERS; ++it) {
        kmeans_iter_k<<<dim3(NB, Bn), 256, 0, stream>>>(x, feat_t, cent, cnorm, idxg, gpart);
        update_cent_k<<<64, 256, 0, stream>>>(gpart, cent, cnorm);
    }
    assign_final_k<<<dim3(NB, Bn), 256, 0, stream>>>(x, cent, cnorm, idxg,
                                                     out + (size_t)Bn * On * Np);

    centp_partial_k<<<dim3(NBP, Bn), 576, 0, stream>>>(feat_t, idxg, gpartp);
    centp_att_k<<<dim3(Sc, Bn), 576, 0, stream>>>(gpartp, kg_w, kg_b, attb);

    final_out_k<<<dim3(Np / 64, Bn), 256, 0, stream>>>(x, feat_t, idxg, attb, w2bf, b2, out);
}

// Round 2
// 595.773 us; speedup vs baseline: 1.3409x; 1.3409x over previous
//
#include <hip/hip_runtime.h>
#include <hip/hip_bf16.h>

#define Bn 8
#define Cn 64
#define Hh 128
#define Wi 128
#define Np 16384      // H*W
#define Sc 32         // clusters
#define On 64         // output channels
#define Dd 576        // C*9
#define KM_ITERS 8
#define NB 64         // kmeans blocks per batch (256 px each)
#define KBLK 32       // centp GEMM blocks per batch (512 px each)

typedef float f32x4 __attribute__((ext_vector_type(4)));
typedef __bf16 bf16x8 __attribute__((ext_vector_type(8)));
typedef __bf16 bf16x4 __attribute__((ext_vector_type(4)));
typedef short short8v __attribute__((ext_vector_type(8)));

// ---------------- transpose x[b][c][n] -> feat_t[b][n][c] ----------------
__global__ __launch_bounds__(256) void transpose_k(const float* __restrict__ x,
                                                   float* __restrict__ feat_t) {
    __shared__ float tile[64][65];
    int b = blockIdx.y, n0 = blockIdx.x * 64, t = threadIdx.x;
    int j = t & 63, c0 = (t >> 6) * 16;
    for (int cc = 0; cc < 16; ++cc) {
        int c = c0 + cc;
        tile[c][j] = x[((size_t)b * Cn + c) * Np + n0 + j];
    }
    __syncthreads();
    int cr = t & 63, j0 = (t >> 6) * 16;
    for (int jj = 0; jj < 16; ++jj) {
        int j2 = j0 + jj;
        feat_t[((size_t)b * Np + n0 + j2) * Cn + cr] = tile[cr][j2];
    }
}

// ---------------- centroid init ----------------
__global__ __launch_bounds__(64) void init_cent_k(const float* __restrict__ x,
                                                  float* __restrict__ cent,
                                                  float* __restrict__ cnorm) {
    int b = blockIdx.y, s = blockIdx.x, c = threadIdx.x;
    int n = s * (Np / Sc);
    float v = x[((size_t)b * Cn + c) * Np + n];
    cent[(b * Sc + s) * Cn + c] = v;
    float sq = v * v;
    #pragma unroll
    for (int off = 32; off >= 1; off >>= 1) sq += __shfl_down(sq, off);
    if (c == 0) cnorm[b * Sc + s] = sq;
}

// ---------------- w2 -> bf16, permuted to [k][o][c] ----------------
__global__ __launch_bounds__(256) void w2prep_k(const float* __restrict__ w2,
                                                __bf16* __restrict__ w2kg) {
    int i = blockIdx.x * 256 + threadIdx.x;   // 36864 total
    int k = i >> 12, rem = i & 4095, o = rem >> 6, c = rem & 63;
    w2kg[i] = (__bf16)w2[o * Dd + c * 9 + k];
}

// ---------------- assignment helper (f32, strict-< argmin) ----------------
__device__ __forceinline__ int assign_pixel(const float* __restrict__ x,
                                            const float cent_s[Sc][Cn],
                                            const float* cnorm_s, int b, int n) {
    float acc[Sc];
    #pragma unroll
    for (int s = 0; s < Sc; ++s) acc[s] = 0.f;
    #pragma unroll 4
    for (int c = 0; c < Cn; ++c) {
        float f = x[((size_t)b * Cn + c) * Np + n];
        #pragma unroll
        for (int s = 0; s < Sc; ++s) acc[s] = fmaf(f, cent_s[s][c], acc[s]);
    }
    int best = 0;
    float bd = cnorm_s[0] - 2.f * acc[0];
    #pragma unroll
    for (int s = 1; s < Sc; ++s) {
        float d = cnorm_s[s] - 2.f * acc[s];
        if (d < bd) { bd = d; best = s; }
    }
    return best;
}

// ---------------- one Lloyd iteration ----------------
__global__ __launch_bounds__(256) void kmeans_iter_k(const float* __restrict__ x,
                                                     const float* __restrict__ feat_t,
                                                     const float* __restrict__ cent,
                                                     const float* __restrict__ cnorm,
                                                     int* __restrict__ idxg,
                                                     float* __restrict__ gpart) {
    __shared__ float cent_s[Sc][Cn];
    __shared__ float cnorm_s[Sc];
    __shared__ int   idx_s[256];
    __shared__ float part[4][Sc][Cn + 1];
    int b = blockIdx.y, n0 = blockIdx.x * 256, t = threadIdx.x;

    for (int i = t; i < Sc * Cn; i += 256) ((float*)cent_s)[i] = cent[b * Sc * Cn + i];
    if (t < Sc) cnorm_s[t] = cnorm[b * Sc + t];
    for (int i = t; i < 4 * Sc * (Cn + 1); i += 256) ((float*)part)[i] = 0.f;
    __syncthreads();

    int n = n0 + t;
    int best = assign_pixel(x, cent_s, cnorm_s, b, n);
    idx_s[t] = best;
    idxg[b * Np + n] = best;
    __syncthreads();

    int w = t >> 6, c = t & 63;
    for (int p = 0; p < 64; ++p) {
        int pp = w * 64 + p;
        int s = idx_s[pp];
        float v = feat_t[((size_t)b * Np + n0 + pp) * Cn + c];
        part[w][s][c] += v;
        if (c == 0) part[w][s][Cn] += 1.f;
    }
    __syncthreads();

    const int plane = Sc * (Cn + 1);
    float* gp = gpart + (size_t)(b * NB + blockIdx.x) * plane;
    const float* p0 = (const float*)part;
    for (int i = t; i < plane; i += 256)
        gp[i] = p0[i] + p0[plane + i] + p0[2 * plane + i] + p0[3 * plane + i];
}

// ---------------- reduce partials -> new centroids ----------------
__global__ __launch_bounds__(256) void update_cent_k(const float* __restrict__ gpart,
                                                     float* __restrict__ cent,
                                                     float* __restrict__ cnorm) {
    int t = threadIdx.x;
    int pair = blockIdx.x * 4 + (t >> 6);
    int b = pair >> 5, s = pair & 31, c = t & 63;
    float sum = 0.f, cnt = 0.f;
    for (int blk = 0; blk < NB; ++blk) {
        const float* g = gpart + ((size_t)(b * NB + blk) * Sc + s) * (Cn + 1);
        sum += g[c];
        cnt += g[Cn];
    }
    float ce = sum / fmaxf(cnt, 1.f);
    cent[(b * Sc + s) * Cn + c] = ce;
    float sq = ce * ce;
    #pragma unroll
    for (int off = 32; off >= 1; off >>= 1) sq += __shfl_down(sq, off);
    if (c == 0) cnorm[b * Sc + s] = sq;
}

// ---------------- final assignment ----------------
__global__ __launch_bounds__(256) void assign_final_k(const float* __restrict__ x,
                                                      const float* __restrict__ cent,
                                                      const float* __restrict__ cnorm,
                                                      int* __restrict__ idxg,
                                                      float* __restrict__ out_idx) {
    __shared__ float cent_s[Sc][Cn];
    __shared__ float cnorm_s[Sc];
    int b = blockIdx.y, n0 = blockIdx.x * 256, t = threadIdx.x;
    for (int i = t; i < Sc * Cn; i += 256) ((float*)cent_s)[i] = cent[b * Sc * Cn + i];
    if (t < Sc) cnorm_s[t] = cnorm[b * Sc + t];
    __syncthreads();
    int n = n0 + t;
    int best = assign_pixel(x, cent_s, cnorm_s, b, n);
    idxg[b * Np + n] = best;
    out_idx[b * Np + n] = (float)best;
}

// ---------------- cluster patch sums via one-hot MFMA GEMM ----------------
// partialP[b][kb][r=s*9+k][c] = sum over this block's 512 pixels m of
//   [idx[m - delta_k] == s && valid] * feat[m][c]
__global__ __launch_bounds__(512) void centp_mfma_k(const float* __restrict__ x,
                                                    const int* __restrict__ idxg,
                                                    float* __restrict__ partialP) {
    __shared__ __bf16 Amat[288 * 56];  // 18 M-tiles x K=32, stride 56 (2-way banks)
    __shared__ __bf16 Bt[64 * 56];     // B^T: [c][k] so B-frag reads are contiguous
    int b = blockIdx.y, kb = blockIdx.x, t = threadIdx.x;
    int w = t >> 6, l = t & 63;
    int wm = w >> 2, wn = w & 3;       // 2 x 4 wave grid
    int arow = l & 15, kg = l >> 4;
    f32x4 acc[9];
    #pragma unroll
    for (int j = 0; j < 9; ++j) acc[j] = (f32x4){0.f, 0.f, 0.f, 0.f};

    int m_base = kb * 512;
    for (int kt = 0; kt < 16; ++kt) {
        int m0 = m_base + kt * 32;
        // zero A cols 0..31 (9 dword stores per thread)
        #pragma unroll
        for (int j = 0; j < 9; ++j) {
            int i = t + 512 * j;
            int row = i >> 4, dc = i & 15;
            *(unsigned*)&Amat[row * 56 + dc * 2] = 0u;
        }
        // stage Bt[c][kk] = x[b][c][m0+kk] (coalesced from x, no transpose needed)
        {
            int c = t >> 3, k0 = (t & 7) * 4;
            f32x4 v = *(const f32x4*)&x[((size_t)b * Cn + c) * Np + m0 + k0];
            bf16x4 bv4;
            bv4[0] = (__bf16)v.x; bv4[1] = (__bf16)v.y;
            bv4[2] = (__bf16)v.z; bv4[3] = (__bf16)v.w;
            *(bf16x4*)&Bt[c * 56 + k0] = bv4;
        }
        __syncthreads();
        // scatter one-hot entries
        if (t < 288) {
            int m = t & 31, k = t >> 5;
            int mg = m0 + m, mh = mg >> 7, mw = mg & 127;
            int dh = k / 3 - 1, dw = k % 3 - 1;
            int nh = mh - dh, nw = mw - dw;
            if (((unsigned)nh < 128u) && ((unsigned)nw < 128u)) {
                int s = idxg[b * Np + (nh << 7) + nw];
                Amat[(s * 9 + k) * 56 + m] = (__bf16)1.0f;
            }
        }
        __syncthreads();
        // MFMA: wave (wm,wn) owns M-rows [wm*144, +144), N-cols [wn*16, +16)
        bf16x8 bfrag = *(const bf16x8*)&Bt[(wn * 16 + arow) * 56 + kg * 8];
        #pragma unroll
        for (int j = 0; j < 9; ++j) {
            int mt = wm * 9 + j;
            bf16x8 afrag = *(const bf16x8*)&Amat[(mt * 16 + arow) * 56 + kg * 8];
            acc[j] = __builtin_amdgcn_mfma_f32_16x16x32_bf16(afrag, bfrag, acc[j], 0, 0, 0);
        }
        __syncthreads();
    }
    float* P = partialP + (size_t)(b * KBLK + kb) * 288 * 64;
    #pragma unroll
    for (int j = 0; j < 9; ++j) {
        int R0 = (wm * 9 + j) * 16 + kg * 4;
        int col = wn * 16 + arow;
        #pragma unroll
        for (int r = 0; r < 4; ++r) P[(size_t)(R0 + r) * 64 + col] = acc[j][r];
    }
}

// ---------------- reduce partials + counts -> softmax attention ----------------
__global__ __launch_bounds__(576) void centp_att2_k(const float* __restrict__ partialP,
                                                    const int* __restrict__ idxg,
                                                    const float* __restrict__ kg_w,
                                                    const float* __restrict__ kg_b,
                                                    float* __restrict__ attb) {
    __shared__ float cpm[9][64];
    __shared__ float logit[9];
    __shared__ int   redint[9];
    __shared__ float cnt_sh;
    int b = blockIdx.y, s = blockIdx.x, t = threadIdx.x;
    int k = t >> 6, c = t & 63;

    float sum = 0.f;
    for (int kb = 0; kb < KBLK; ++kb)
        sum += partialP[((size_t)(b * KBLK + kb) * 288 + s * 9 + k) * 64 + c];

    // deterministic integer count of cluster s
    int cloc = 0;
    for (int i = t; i < Np; i += 576) cloc += (idxg[b * Np + i] == s);
    #pragma unroll
    for (int off = 32; off >= 1; off >>= 1) cloc += __shfl_down(cloc, off);
    if ((t & 63) == 0) redint[k] = cloc;
    __syncthreads();
    if (t == 0) {
        int c2 = 0;
        #pragma unroll
        for (int j = 0; j < 9; ++j) c2 += redint[j];
        cnt_sh = fmaxf((float)c2, 1.f);
    }
    __syncthreads();
    cpm[k][c] = sum / cnt_sh;
    __syncthreads();

    // logits: j = k (9 waves), lane = c; dot over (c,u): kg_w[j][c*9+u]
    float pr = 0.f;
    #pragma unroll
    for (int u = 0; u < 9; ++u)
        pr = fmaf(cpm[u][c], kg_w[k * Dd + c * 9 + u], pr);
    #pragma unroll
    for (int off = 32; off >= 1; off >>= 1) pr += __shfl_down(pr, off);
    if ((t & 63) == 0) logit[k] = pr + kg_b[k];
    __syncthreads();
    if (t == 0) {
        float mx = logit[0];
        #pragma unroll
        for (int jj = 1; jj < 9; ++jj) mx = fmaxf(mx, logit[jj]);
        float e[9], sm = 0.f;
        #pragma unroll
        for (int jj = 0; jj < 9; ++jj) { e[jj] = expf(logit[jj] - mx); sm += e[jj]; }
        #pragma unroll
        for (int jj = 0; jj < 9; ++jj) attb[(b * Sc + s) * 9 + jj] = e[jj] / sm * 9.f;
    }
}

// ---------------- final: y = sum_k att_k * (shift_k(feat) @ w2_k^T) ----------------
__global__ __launch_bounds__(256) void final_out2_k(const float* __restrict__ x,
                                                    const float* __restrict__ feat_t,
                                                    const int* __restrict__ idxg,
                                                    const float* __restrict__ attb,
                                                    const __bf16* __restrict__ w2kg,
                                                    const float* __restrict__ b2,
                                                    float* __restrict__ out) {
    __shared__ __align__(16) char smem[18432];       // w2s[2][64][72] bf16  /  trans[64][68] f32
    __shared__ float apix[64][10];
    __bf16 (*w2s)[64][72] = (__bf16 (*)[64][72])smem;
    float (*trans)[68]    = (float (*)[68])smem;

    int b = blockIdx.y, n0 = blockIdx.x * 64, t = threadIdx.x;
    if (t < 64) {
        int s = idxg[b * Np + n0 + t];
        const float* ap = attb + (b * Sc + s) * 9;
        #pragma unroll
        for (int k = 0; k < 9; ++k) apix[t][k] = ap[k];
        apix[t][9] = b2[t];
    }
    // stage w2 k=0
    for (int q = t; q < 512; q += 256) {
        int o = q >> 3, c0 = (q & 7) * 8;
        *(bf16x8*)&w2s[0][o][c0] = *(const bf16x8*)&w2kg[(size_t)0 * 4096 + o * 64 + c0];
    }
    __syncthreads();

    int w = t >> 6, l = t & 63;
    int arow = l & 15, kg = l >> 4;
    int px = w * 16 + arow;
    int n = n0 + px, hh = n >> 7, ww = n & 127;
    f32x4 acc[4];
    #pragma unroll
    for (int nt = 0; nt < 4; ++nt) acc[nt] = (f32x4){0.f, 0.f, 0.f, 0.f};

    for (int k = 0; k < 9; ++k) {
        int cur = k & 1;
        if (k < 8) {  // stage next buffer (no extra barrier needed: disjoint halves)
            for (int q = t; q < 512; q += 256) {
                int o = q >> 3, c0 = (q & 7) * 8;
                *(bf16x8*)&w2s[cur ^ 1][o][c0] =
                    *(const bf16x8*)&w2kg[(size_t)(k + 1) * 4096 + o * 64 + c0];
            }
        }
        int dh = k / 3 - 1, dw = k % 3 - 1;
        int h2 = hh + dh, w2c = ww + dw;
        bool valid = ((unsigned)h2 < 128u) && ((unsigned)w2c < 128u);
        const float* fr = feat_t + ((size_t)b * Np + (h2 << 7) + w2c) * Cn;
        float a = apix[px][k];
        #pragma unroll
        for (int ks = 0; ks < 2; ++ks) {
            f32x4 v0 = (f32x4){0.f, 0.f, 0.f, 0.f}, v1 = v0;
            if (valid) {
                v0 = *(const f32x4*)&fr[ks * 32 + kg * 8];
                v1 = *(const f32x4*)&fr[ks * 32 + kg * 8 + 4];
            }
            bf16x8 av;
            av[0] = (__bf16)(v0.x * a); av[1] = (__bf16)(v0.y * a);
            av[2] = (__bf16)(v0.z * a); av[3] = (__bf16)(v0.w * a);
            av[4] = (__bf16)(v1.x * a); av[5] = (__bf16)(v1.y * a);
            av[6] = (__bf16)(v1.z * a); av[7] = (__bf16)(v1.w * a);
            #pragma unroll
            for (int nt = 0; nt < 4; ++nt) {
                bf16x8 bv = *(const bf16x8*)&w2s[cur][nt * 16 + arow][ks * 32 + kg * 8];
                acc[nt] = __builtin_amdgcn_mfma_f32_16x16x32_bf16(av, bv, acc[nt], 0, 0, 0);
            }
        }
        __syncthreads();
    }

    // epilogue: transpose through LDS (w2s buffer reused; barrier above protects)
    #pragma unroll
    for (int nt = 0; nt < 4; ++nt) {
        #pragma unroll
        for (int r = 0; r < 4; ++r)
            trans[nt * 16 + arow][w * 16 + kg * 4 + r] = acc[nt][r];
    }
    __syncthreads();
    for (int i = t; i < 4096; i += 256) {
        int o = i >> 6, p2 = i & 63;
        size_t gi = ((size_t)b * On + o) * Np + n0 + p2;
        out[gi] = x[gi] + trans[o][p2] + apix[o][9];
    }
}

extern "C" void kernel_launch(void* const* d_in, const int* in_sizes, int n_in,
                              void* d_out, int out_size, void* d_ws, size_t ws_size,
                              hipStream_t stream) {
    (void)in_sizes; (void)n_in; (void)out_size; (void)ws_size;
    const float* x    = (const float*)d_in[0];
    const float* kg_w = (const float*)d_in[5];
    const float* kg_b = (const float*)d_in[6];
    const float* w2   = (const float*)d_in[7];
    const float* b2   = (const float*)d_in[8];
    float* out = (float*)d_out;

    float* ws       = (float*)d_ws;
    float* feat_t   = ws;                                        // 8,388,608 f
    float* cent     = feat_t + (size_t)Bn * Np * Cn;             // 16,384
    float* cnorm    = cent + Bn * Sc * Cn;                       // 256
    int*   idxg     = (int*)(cnorm + Bn * Sc);                   // 131,072
    float* gpart    = (float*)(idxg + Bn * Np);                  // 1,064,960
    float* partialP = gpart + (size_t)Bn * NB * Sc * (Cn + 1);   // 4,718,592
    float* attb     = partialP + (size_t)Bn * KBLK * 288 * 64;   // 2,304
    __bf16* w2kg    = (__bf16*)(attb + Bn * Sc * 9);             // 36,864 bf16

    transpose_k<<<dim3(Np / 64, Bn), 256, 0, stream>>>(x, feat_t);
    init_cent_k<<<dim3(Sc, Bn), 64, 0, stream>>>(x, cent, cnorm);
    w2prep_k<<<(On * Dd) / 256, 256, 0, stream>>>(w2, w2kg);

    for (int it = 0; it < KM_ITERS; ++it) {
        kmeans_iter_k<<<dim3(NB, Bn), 256, 0, stream>>>(x, feat_t, cent, cnorm, idxg, gpart);
        update_cent_k<<<64, 256, 0, stream>>>(gpart, cent, cnorm);
    }
    assign_final_k<<<dim3(NB, Bn), 256, 0, stream>>>(x, cent, cnorm, idxg,
                                                     out + (size_t)Bn * On * Np);

    centp_mfma_k<<<dim3(KBLK, Bn), 512, 0, stream>>>(x, idxg, partialP);
    centp_att2_k<<<dim3(Sc, Bn), 576, 0, stream>>>(partialP, idxg, kg_w, kg_b, attb);

    final_out2_k<<<dim3(Np / 64, Bn), 256, 0, stream>>>(x, feat_t, idxg, attb, w2kg, b2, out);
}

// Round 4
// 510.766 us; speedup vs baseline: 1.5640x; 1.1664x over previous
//
#include <hip/hip_runtime.h>
#include <hip/hip_bf16.h>

#define Bn 8
#define Cn 64
#define Np 16384      // H*W
#define Sc 32         // clusters
#define On 64         // output channels
#define Dd 576        // C*9
#define KM_ITERS 8
#define KMB 64        // kmeans blocks per batch (256 px each)
#define KBLK 32       // centp GEMM blocks per batch (512 px each)

typedef float f32x4 __attribute__((ext_vector_type(4)));
typedef __bf16 bf16x8 __attribute__((ext_vector_type(8)));
typedef __bf16 bf16x4 __attribute__((ext_vector_type(4)));

__device__ __forceinline__ void split3(float v, __bf16& h, __bf16& m, __bf16& lo) {
    h = (__bf16)v;
    float r = v - (float)h;
    m = (__bf16)r;
    lo = (__bf16)(r - (float)m);
}

// ---------------- x[b][c][n] -> fh/fm/fl[b][n][c] (bf16 3-term split) ----------------
__global__ __launch_bounds__(256) void featbf3_k(const float* __restrict__ x,
                                                 __bf16* __restrict__ fh,
                                                 __bf16* __restrict__ fm,
                                                 __bf16* __restrict__ fl) {
    __shared__ float tile[64][65];
    int b = blockIdx.y, n0 = blockIdx.x * 64, t = threadIdx.x;
    int j = t & 63, c0 = (t >> 6) * 16;
    #pragma unroll
    for (int cc = 0; cc < 16; ++cc)
        tile[c0 + cc][j] = x[((size_t)b * Cn + c0 + cc) * Np + n0 + j];
    __syncthreads();
    int n_loc = t & 63, cq = (t >> 6) * 16;
    bf16x8 vh[2], vm[2], vl[2];
    #pragma unroll
    for (int g = 0; g < 2; ++g)
        #pragma unroll
        for (int u = 0; u < 8; ++u) {
            __bf16 h, m, lo;
            split3(tile[cq + g * 8 + u][n_loc], h, m, lo);
            vh[g][u] = h; vm[g][u] = m; vl[g][u] = lo;
        }
    size_t base = ((size_t)b * Np + n0 + n_loc) * Cn + cq;
    *(bf16x8*)&fh[base] = vh[0]; *(bf16x8*)&fh[base + 8] = vh[1];
    *(bf16x8*)&fm[base] = vm[0]; *(bf16x8*)&fm[base + 8] = vm[1];
    *(bf16x8*)&fl[base] = vl[0]; *(bf16x8*)&fl[base + 8] = vl[1];
}

// ---------------- centroid init (f32 + 3-term bf16 + cnorm) ----------------
__global__ __launch_bounds__(64) void init_cent3_k(const float* __restrict__ x,
                                                   float* __restrict__ cent_f32,
                                                   __bf16* __restrict__ ch_,
                                                   __bf16* __restrict__ cm_,
                                                   __bf16* __restrict__ cl_,
                                                   float* __restrict__ cnorm) {
    int b = blockIdx.y, s = blockIdx.x, c = threadIdx.x;
    int n = s * (Np / Sc);
    float v = x[((size_t)b * Cn + c) * Np + n];
    int o = (b * Sc + s) * Cn + c;
    cent_f32[o] = v;
    __bf16 h, m, lo; split3(v, h, m, lo);
    ch_[o] = h; cm_[o] = m; cl_[o] = lo;
    float sq = v * v;
    #pragma unroll
    for (int off = 32; off >= 1; off >>= 1) sq += __shfl_down(sq, off);
    if (c == 0) cnorm[b * Sc + s] = sq;
}

// ---------------- w2 -> bf16, permuted to [k][o][c] ----------------
__global__ __launch_bounds__(256) void w2prep_k(const float* __restrict__ w2,
                                                __bf16* __restrict__ w2kg) {
    int i = blockIdx.x * 256 + threadIdx.x;   // 36864 total
    int k = i >> 12, rem = i & 4095, o = rem >> 6, c = rem & 63;
    w2kg[i] = (__bf16)w2[o * Dd + c * 9 + k];
}

// ---------------- fused Lloyd iteration: MFMA assign (6-product) + exact fallback + MFMA update ----------------
__global__ __launch_bounds__(256, 2) void kmeans_fused2_k(
        const float* __restrict__ x,
        const __bf16* __restrict__ fh, const __bf16* __restrict__ fm, const __bf16* __restrict__ fl,
        const float* __restrict__ cent_f32,
        const __bf16* __restrict__ ch_, const __bf16* __restrict__ cm_, const __bf16* __restrict__ cl_,
        const float* __restrict__ cnorm,
        int* __restrict__ idxg, float* __restrict__ gpart,
        float* __restrict__ out_idx, int do_update) {
    __shared__ __bf16 Bt_h[64][72];
    __shared__ __bf16 Bt_m[64][72];
    __shared__ __bf16 Bt_l[64][72];
    __shared__ __bf16 A_oh[32][72];
    __shared__ int idx_s[256];
    __shared__ int redint[4][32];
    __shared__ float centf_s[32][64];
    __shared__ float cnorm_s[32];
    int b = blockIdx.y, n0 = blockIdx.x * 256, t = threadIdx.x;
    int w = t >> 6, l = t & 63, arow = l & 15, kg = l >> 4;

    // stage f32 centroids + norms (for exact fallback)
    for (int i = t; i < Sc * Cn; i += 256) ((float*)centf_s)[i] = cent_f32[b * Sc * Cn + i];
    if (t < Sc) cnorm_s[t] = cnorm[b * Sc + t];

    // ---- phase A: scores via 3-term split MFMA (6 products) ----
    bf16x8 cbh[2][2], cbm[2][2], cbl[2][2];
    #pragma unroll
    for (int st = 0; st < 2; ++st)
        #pragma unroll
        for (int kt = 0; kt < 2; ++kt) {
            size_t cb = (size_t)(b * Sc + st * 16 + arow) * Cn + kt * 32 + kg * 8;
            cbh[st][kt] = *(const bf16x8*)&ch_[cb];
            cbm[st][kt] = *(const bf16x8*)&cm_[cb];
            cbl[st][kt] = *(const bf16x8*)&cl_[cb];
        }
    float cn0 = cnorm[b * Sc + arow];
    float cn1 = cnorm[b * Sc + 16 + arow];

    f32x4 dacc[4][2];
    #pragma unroll
    for (int mt = 0; mt < 4; ++mt) {
        dacc[mt][0] = (f32x4){0.f, 0.f, 0.f, 0.f};
        dacc[mt][1] = (f32x4){0.f, 0.f, 0.f, 0.f};
    }
    #pragma unroll
    for (int mt = 0; mt < 4; ++mt) {
        size_t fb = ((size_t)b * Np + n0 + w * 64 + mt * 16 + arow) * Cn;
        bf16x8 ah[2], am2[2], al2[2];
        #pragma unroll
        for (int kt = 0; kt < 2; ++kt) {
            ah[kt]  = *(const bf16x8*)&fh[fb + kt * 32 + kg * 8];
            am2[kt] = *(const bf16x8*)&fm[fb + kt * 32 + kg * 8];
            al2[kt] = *(const bf16x8*)&fl[fb + kt * 32 + kg * 8];
        }
        #pragma unroll
        for (int st = 0; st < 2; ++st)
            #pragma unroll
            for (int kt = 0; kt < 2; ++kt) {
                dacc[mt][st] = __builtin_amdgcn_mfma_f32_16x16x32_bf16(ah[kt],  cbh[st][kt], dacc[mt][st], 0, 0, 0);
                dacc[mt][st] = __builtin_amdgcn_mfma_f32_16x16x32_bf16(ah[kt],  cbm[st][kt], dacc[mt][st], 0, 0, 0);
                dacc[mt][st] = __builtin_amdgcn_mfma_f32_16x16x32_bf16(am2[kt], cbh[st][kt], dacc[mt][st], 0, 0, 0);
                dacc[mt][st] = __builtin_amdgcn_mfma_f32_16x16x32_bf16(ah[kt],  cbl[st][kt], dacc[mt][st], 0, 0, 0);
                dacc[mt][st] = __builtin_amdgcn_mfma_f32_16x16x32_bf16(al2[kt], cbh[st][kt], dacc[mt][st], 0, 0, 0);
                dacc[mt][st] = __builtin_amdgcn_mfma_f32_16x16x32_bf16(am2[kt], cbm[st][kt], dacc[mt][st], 0, 0, 0);
            }
    }
    __syncthreads();   // centf_s staged before fallback may read it

    // argmin + top-2 gap + exact fallback for near-ties
    #pragma unroll
    for (int mt = 0; mt < 4; ++mt)
        #pragma unroll
        for (int r = 0; r < 4; ++r) {
            float dA = cn0 - 2.f * dacc[mt][0][r];
            float dB = cn1 - 2.f * dacc[mt][1][r];
            float d1, d2; int s1;
            if (dB < dA) { d1 = dB; s1 = arow + 16; d2 = dA; }
            else         { d1 = dA; s1 = arow;      d2 = dB; }
            #pragma unroll
            for (int mk = 1; mk < 16; mk <<= 1) {
                float d1o = __shfl_xor(d1, mk);
                int   s1o = __shfl_xor(s1, mk);
                float d2o = __shfl_xor(d2, mk);
                float big = fmaxf(d1, d1o);
                d2 = fminf(fminf(d2, d2o), big);
                if (d1o < d1 || (d1o == d1 && s1o < s1)) { d1 = d1o; s1 = s1o; }
            }
            int pix = w * 64 + mt * 16 + kg * 4 + r;
            bool writer = (arow == 0);
            if (writer) idx_s[pix] = s1;
            bool flag = writer && ((d2 - d1) < 1e-4f * (1.f + fabsf(d1)));
            unsigned long long bal = __ballot(flag);
            while (bal) {
                int src = __ffsll(bal) - 1;
                bal &= bal - 1;
                int fp = w * 64 + mt * 16 + (src >> 4) * 4 + r;
                int n = n0 + fp;
                int s = l & 31, c0 = (l >> 5) * 32;
                float acc2 = 0.f;
                #pragma unroll 8
                for (int c = 0; c < 32; ++c)
                    acc2 = fmaf(x[((size_t)b * Cn + c0 + c) * Np + n], centf_s[s][c0 + c], acc2);
                acc2 += __shfl_xor(acc2, 32);
                float dd = cnorm_s[s] - 2.f * acc2;
                int ss = s;
                #pragma unroll
                for (int mk = 1; mk < 32; mk <<= 1) {
                    float ddo = __shfl_xor(dd, mk);
                    int   sso = __shfl_xor(ss, mk);
                    if (ddo < dd || (ddo == dd && sso < ss)) { dd = ddo; ss = sso; }
                }
                if (l == 0) idx_s[fp] = ss;
            }
        }
    __syncthreads();

    int best = idx_s[t];
    idxg[b * Np + n0 + t] = best;
    if (out_idx) out_idx[b * Np + n0 + t] = (float)best;
    if (!do_update) return;

    // deterministic counts via ballot
    #pragma unroll 4
    for (int s = 0; s < Sc; ++s) {
        unsigned long long bal = __ballot(best == s);
        if (l == 0) redint[w][s] = __popcll(bal);
    }

    // ---- phase B: per-block cluster sums via one-hot MFMA (3-term B) ----
    f32x4 uacc[2];
    uacc[0] = (f32x4){0.f, 0.f, 0.f, 0.f};
    uacc[1] = (f32x4){0.f, 0.f, 0.f, 0.f};
    for (int mc = 0; mc < 4; ++mc) {
        __syncthreads();
        {   // stage Bt chunk [c][64 m] 3-term from x (coalesced channel-major)
            int c = t >> 2, mq = t & 3;
            const float* xp = &x[((size_t)b * Cn + c) * Np + n0 + mc * 64 + mq * 16];
            #pragma unroll
            for (int u = 0; u < 4; ++u) {
                f32x4 v = *(const f32x4*)&xp[u * 4];
                bf16x4 hv, mv, lv;
                #pragma unroll
                for (int e = 0; e < 4; ++e) {
                    __bf16 h, m, lo; split3(v[e], h, m, lo);
                    hv[e] = h; mv[e] = m; lv[e] = lo;
                }
                *(bf16x4*)&Bt_h[c][mq * 16 + u * 4] = hv;
                *(bf16x4*)&Bt_m[c][mq * 16 + u * 4] = mv;
                *(bf16x4*)&Bt_l[c][mq * 16 + u * 4] = lv;
            }
        }
        {   // build one-hot A columns
            int m = t & 63, sq = t >> 6;
            int bm = idx_s[mc * 64 + m];
            #pragma unroll
            for (int u = 0; u < 8; ++u)
                A_oh[sq * 8 + u][m] = (sq * 8 + u == bm) ? (__bf16)1.0f : (__bf16)0.0f;
        }
        __syncthreads();
        #pragma unroll
        for (int kh = 0; kh < 2; ++kh) {
            bf16x8 bh = *(const bf16x8*)&Bt_h[w * 16 + arow][kh * 32 + kg * 8];
            bf16x8 bm2 = *(const bf16x8*)&Bt_m[w * 16 + arow][kh * 32 + kg * 8];
            bf16x8 bl2 = *(const bf16x8*)&Bt_l[w * 16 + arow][kh * 32 + kg * 8];
            #pragma unroll
            for (int smt = 0; smt < 2; ++smt) {
                bf16x8 af = *(const bf16x8*)&A_oh[smt * 16 + arow][kh * 32 + kg * 8];
                uacc[smt] = __builtin_amdgcn_mfma_f32_16x16x32_bf16(af, bh,  uacc[smt], 0, 0, 0);
                uacc[smt] = __builtin_amdgcn_mfma_f32_16x16x32_bf16(af, bm2, uacc[smt], 0, 0, 0);
                uacc[smt] = __builtin_amdgcn_mfma_f32_16x16x32_bf16(af, bl2, uacc[smt], 0, 0, 0);
            }
        }
    }
    float* gp = &gpart[(size_t)(b * KMB + blockIdx.x) * (Sc * 65)];
    #pragma unroll
    for (int smt = 0; smt < 2; ++smt)
        #pragma unroll
        for (int r = 0; r < 4; ++r)
            gp[(smt * 16 + kg * 4 + r) * 65 + w * 16 + arow] = uacc[smt][r];
    if (t < Sc)
        gp[t * 65 + 64] = (float)(redint[0][t] + redint[1][t] + redint[2][t] + redint[3][t]);
}

// ---------------- reduce partials -> new centroids (f32 + 3-term + cnorm) ----------------
__global__ __launch_bounds__(64) void update_reduce2_k(const float* __restrict__ gpart,
                                                       float* __restrict__ cent_f32,
                                                       __bf16* __restrict__ ch_,
                                                       __bf16* __restrict__ cm_,
                                                       __bf16* __restrict__ cl_,
                                                       float* __restrict__ cnorm) {
    int b = blockIdx.y, s = blockIdx.x, c = threadIdx.x;
    float sum = 0.f;
    for (int blk = 0; blk < KMB; ++blk)
        sum += gpart[(size_t)(b * KMB + blk) * (Sc * 65) + s * 65 + c];
    float cnt = 0.f;
    if (c == 0)
        for (int blk = 0; blk < KMB; ++blk)
            cnt += gpart[(size_t)(b * KMB + blk) * (Sc * 65) + s * 65 + 64];
    cnt = __shfl(cnt, 0);
    float mean = sum / fmaxf(cnt, 1.f);
    int o = (b * Sc + s) * Cn + c;
    cent_f32[o] = mean;
    __bf16 h, m, lo; split3(mean, h, m, lo);
    ch_[o] = h; cm_[o] = m; cl_[o] = lo;
    float sq = mean * mean;
    #pragma unroll
    for (int off = 32; off >= 1; off >>= 1) sq += __shfl_down(sq, off);
    if (c == 0) cnorm[b * Sc + s] = sq;
}

// ---------------- cluster patch sums via one-hot MFMA GEMM (unchanged, proven R2) ----------------
__global__ __launch_bounds__(512) void centp_mfma_k(const float* __restrict__ x,
                                                    const int* __restrict__ idxg,
                                                    float* __restrict__ partialP) {
    __shared__ __bf16 Amat[288 * 56];
    __shared__ __bf16 Bt[64 * 56];
    int b = blockIdx.y, kb = blockIdx.x, t = threadIdx.x;
    int w = t >> 6, l = t & 63;
    int wm = w >> 2, wn = w & 3;
    int arow = l & 15, kg = l >> 4;
    f32x4 acc[9];
    #pragma unroll
    for (int j = 0; j < 9; ++j) acc[j] = (f32x4){0.f, 0.f, 0.f, 0.f};

    int m_base = kb * 512;
    for (int kt = 0; kt < 16; ++kt) {
        int m0 = m_base + kt * 32;
        #pragma unroll
        for (int j = 0; j < 9; ++j) {
            int i = t + 512 * j;
            int row = i >> 4, dc = i & 15;
            *(unsigned*)&Amat[row * 56 + dc * 2] = 0u;
        }
        {
            int c = t >> 3, k0 = (t & 7) * 4;
            f32x4 v = *(const f32x4*)&x[((size_t)b * Cn + c) * Np + m0 + k0];
            bf16x4 bv4;
            bv4[0] = (__bf16)v.x; bv4[1] = (__bf16)v.y;
            bv4[2] = (__bf16)v.z; bv4[3] = (__bf16)v.w;
            *(bf16x4*)&Bt[c * 56 + k0] = bv4;
        }
        __syncthreads();
        if (t < 288) {
            int m = t & 31, k = t >> 5;
            int mg = m0 + m, mh = mg >> 7, mw = mg & 127;
            int dh = k / 3 - 1, dw = k % 3 - 1;
            int nh = mh - dh, nw = mw - dw;
            if (((unsigned)nh < 128u) && ((unsigned)nw < 128u)) {
                int s = idxg[b * Np + (nh << 7) + nw];
                Amat[(s * 9 + k) * 56 + m] = (__bf16)1.0f;
            }
        }
        __syncthreads();
        bf16x8 bfrag = *(const bf16x8*)&Bt[(wn * 16 + arow) * 56 + kg * 8];
        #pragma unroll
        for (int j = 0; j < 9; ++j) {
            int mt = wm * 9 + j;
            bf16x8 afrag = *(const bf16x8*)&Amat[(mt * 16 + arow) * 56 + kg * 8];
            acc[j] = __builtin_amdgcn_mfma_f32_16x16x32_bf16(afrag, bfrag, acc[j], 0, 0, 0);
        }
        __syncthreads();
    }
    float* P = partialP + (size_t)(b * KBLK + kb) * 288 * 64;
    #pragma unroll
    for (int j = 0; j < 9; ++j) {
        int R0 = (wm * 9 + j) * 16 + kg * 4;
        int col = wn * 16 + arow;
        #pragma unroll
        for (int r = 0; r < 4; ++r) P[(size_t)(R0 + r) * 64 + col] = acc[j][r];
    }
}

// ---------------- reduce patch partials + counts -> softmax attention ----------------
__global__ __launch_bounds__(576) void centp_att2_k(const float* __restrict__ partialP,
                                                    const int* __restrict__ idxg,
                                                    const float* __restrict__ kg_w,
                                                    const float* __restrict__ kg_b,
                                                    float* __restrict__ attb) {
    __shared__ float cpm[9][64];
    __shared__ float logit[9];
    __shared__ int   redint[9];
    __shared__ float cnt_sh;
    int b = blockIdx.y, s = blockIdx.x, t = threadIdx.x;
    int k = t >> 6, c = t & 63;

    float sum = 0.f;
    for (int kb = 0; kb < KBLK; ++kb)
        sum += partialP[((size_t)(b * KBLK + kb) * 288 + s * 9 + k) * 64 + c];

    int cloc = 0;
    for (int i = t; i < Np; i += 576) cloc += (idxg[b * Np + i] == s);
    #pragma unroll
    for (int off = 32; off >= 1; off >>= 1) cloc += __shfl_down(cloc, off);
    if ((t & 63) == 0) redint[k] = cloc;
    __syncthreads();
    if (t == 0) {
        int c2 = 0;
        #pragma unroll
        for (int j = 0; j < 9; ++j) c2 += redint[j];
        cnt_sh = fmaxf((float)c2, 1.f);
    }
    __syncthreads();
    cpm[k][c] = sum / cnt_sh;
    __syncthreads();

    float pr = 0.f;
    #pragma unroll
    for (int u = 0; u < 9; ++u)
        pr = fmaf(cpm[u][c], kg_w[k * Dd + c * 9 + u], pr);
    #pragma unroll
    for (int off = 32; off >= 1; off >>= 1) pr += __shfl_down(pr, off);
    if ((t & 63) == 0) logit[k] = pr + kg_b[k];
    __syncthreads();
    if (t == 0) {
        float mx = logit[0];
        #pragma unroll
        for (int jj = 1; jj < 9; ++jj) mx = fmaxf(mx, logit[jj]);
        float e[9], sm = 0.f;
        #pragma unroll
        for (int jj = 0; jj < 9; ++jj) { e[jj] = expf(logit[jj] - mx); sm += e[jj]; }
        #pragma unroll
        for (int jj = 0; jj < 9; ++jj) attb[(b * Sc + s) * 9 + jj] = e[jj] / sm * 9.f;
    }
}

// ---------------- final: y = sum_k att_k * (shift_k(feat) @ w2_k^T), barrier-free k-loop ----------------
__global__ __launch_bounds__(256, 4) void final_out3_k(const float* __restrict__ x,
                                                       const __bf16* __restrict__ fh,
                                                       const int* __restrict__ idxg,
                                                       const float* __restrict__ attb,
                                                       const __bf16* __restrict__ w2kg,
                                                       const float* __restrict__ b2,
                                                       float* __restrict__ out) {
    __shared__ float trans[64][68];
    __shared__ float apix[64][10];
    int b = blockIdx.y, n0 = blockIdx.x * 64, t = threadIdx.x;
    if (t < 64) {
        int s = idxg[b * Np + n0 + t];
        const float* ap = attb + (b * Sc + s) * 9;
        #pragma unroll
        for (int k = 0; k < 9; ++k) apix[t][k] = ap[k];
        apix[t][9] = b2[t];
    }
    __syncthreads();

    int w = t >> 6, l = t & 63, arow = l & 15, kg = l >> 4;
    int px = w * 16 + arow;
    int n = n0 + px, hh = n >> 7, ww = n & 127;
    f32x4 acc[4];
    #pragma unroll
    for (int nt = 0; nt < 4; ++nt) acc[nt] = (f32x4){0.f, 0.f, 0.f, 0.f};

    for (int k = 0; k < 9; ++k) {
        int dh = k / 3 - 1, dw = k % 3 - 1;
        int h2 = hh + dh, w2c = ww + dw;
        bool valid = ((unsigned)h2 < 128u) && ((unsigned)w2c < 128u);
        float a = apix[px][k];
        const __bf16* fr = fh + ((size_t)b * Np + (h2 << 7) + w2c) * Cn;
        #pragma unroll
        for (int ks = 0; ks < 2; ++ks) {
            bf16x8 raw = (bf16x8)(__bf16)0.0f;
            if (valid) raw = *(const bf16x8*)&fr[ks * 32 + kg * 8];
            bf16x8 avs;
            #pragma unroll
            for (int u = 0; u < 8; ++u) avs[u] = (__bf16)((float)raw[u] * a);
            #pragma unroll
            for (int nt = 0; nt < 4; ++nt) {
                bf16x8 bv = *(const bf16x8*)&w2kg[(size_t)k * 4096 + (nt * 16 + arow) * 64 + ks * 32 + kg * 8];
                acc[nt] = __builtin_amdgcn_mfma_f32_16x16x32_bf16(avs, bv, acc[nt], 0, 0, 0);
            }
        }
    }

    #pragma unroll
    for (int nt = 0; nt < 4; ++nt)
        #pragma unroll
        for (int r = 0; r < 4; ++r)
            trans[nt * 16 + arow][w * 16 + kg * 4 + r] = acc[nt][r];
    __syncthreads();
    for (int i = t; i < 4096; i += 256) {
        int o = i >> 6, p2 = i & 63;
        size_t gi = ((size_t)b * On + o) * Np + n0 + p2;
        out[gi] = x[gi] + trans[o][p2] + apix[o][9];
    }
}

extern "C" void kernel_launch(void* const* d_in, const int* in_sizes, int n_in,
                              void* d_out, int out_size, void* d_ws, size_t ws_size,
                              hipStream_t stream) {
    (void)in_sizes; (void)n_in; (void)out_size; (void)ws_size;
    const float* x    = (const float*)d_in[0];
    const float* kg_w = (const float*)d_in[5];
    const float* kg_b = (const float*)d_in[6];
    const float* w2   = (const float*)d_in[7];
    const float* b2   = (const float*)d_in[8];
    float* out = (float*)d_out;

    char* p = (char*)d_ws;
    __bf16* fh      = (__bf16*)p; p += (size_t)Bn * Np * Cn * 2;     // 16.78 MB
    __bf16* fm      = (__bf16*)p; p += (size_t)Bn * Np * Cn * 2;     // 16.78 MB
    __bf16* fl      = (__bf16*)p; p += (size_t)Bn * Np * Cn * 2;     // 16.78 MB
    float*  cent_f32= (float*)p;  p += (size_t)Bn * Sc * Cn * 4;
    __bf16* ch_     = (__bf16*)p; p += (size_t)Bn * Sc * Cn * 2;
    __bf16* cm_     = (__bf16*)p; p += (size_t)Bn * Sc * Cn * 2;
    __bf16* cl_     = (__bf16*)p; p += (size_t)Bn * Sc * Cn * 2;
    float*  cnorm   = (float*)p;  p += (size_t)Bn * Sc * 4;
    int*    idxg    = (int*)p;    p += (size_t)Bn * Np * 4;
    float*  gpart   = (float*)p;  p += (size_t)Bn * KMB * Sc * 65 * 4;      // 4.26 MB
    float*  partialP= (float*)p;  p += (size_t)Bn * KBLK * 288 * 64 * 4;    // 18.87 MB
    float*  attb    = (float*)p;  p += (size_t)Bn * Sc * 9 * 4;
    __bf16* w2kg    = (__bf16*)p; p += (size_t)9 * On * Cn * 2;

    featbf3_k<<<dim3(Np / 64, Bn), 256, 0, stream>>>(x, fh, fm, fl);
    init_cent3_k<<<dim3(Sc, Bn), 64, 0, stream>>>(x, cent_f32, ch_, cm_, cl_, cnorm);
    w2prep_k<<<(On * Dd) / 256, 256, 0, stream>>>(w2, w2kg);

    for (int it = 0; it < KM_ITERS; ++it) {
        kmeans_fused2_k<<<dim3(KMB, Bn), 256, 0, stream>>>(
            x, fh, fm, fl, cent_f32, ch_, cm_, cl_, cnorm, idxg, gpart, nullptr, 1);
        update_reduce2_k<<<dim3(Sc, Bn), 64, 0, stream>>>(gpart, cent_f32, ch_, cm_, cl_, cnorm);
    }
    // final assignment (writes idx int + float output chunk)
    kmeans_fused2_k<<<dim3(KMB, Bn), 256, 0, stream>>>(
        x, fh, fm, fl, cent_f32, ch_, cm_, cl_, cnorm, idxg, gpart,
        out + (size_t)Bn * On * Np, 0);

    centp_mfma_k<<<dim3(KBLK, Bn), 512, 0, stream>>>(x, idxg, partialP);
    centp_att2_k<<<dim3(Sc, Bn), 576, 0, stream>>>(partialP, idxg, kg_w, kg_b, attb);

    final_out3_k<<<dim3(Np / 64, Bn), 256, 0, stream>>>(x, fh, idxg, attb, w2kg, b2, out);
}

// Round 5
// 392.857 us; speedup vs baseline: 2.0334x; 1.3001x over previous
//
#include <hip/hip_runtime.h>
#include <hip/hip_bf16.h>

#define Bn 8
#define Cn 64
#define Np 16384      // H*W
#define Sc 32         // clusters
#define On 64         // output channels
#define Dd 576        // C*9
#define KM_ITERS 8
#define KMB 64        // kmeans blocks per batch (256 px each)
#define KBLK 32       // centp GEMM blocks per batch (512 px each)

typedef float f32x4 __attribute__((ext_vector_type(4)));
typedef __bf16 bf16x8 __attribute__((ext_vector_type(8)));
typedef __bf16 bf16x4 __attribute__((ext_vector_type(4)));

__device__ __forceinline__ void split3(float v, __bf16& h, __bf16& m, __bf16& lo) {
    h = (__bf16)v;
    float r = v - (float)h;
    m = (__bf16)r;
    lo = (__bf16)(r - (float)m);
}

// ---------------- x[b][c][n] -> fh/fm/fl[b][n][c] (bf16 3-term split) ----------------
__global__ __launch_bounds__(256) void featbf3_k(const float* __restrict__ x,
                                                 __bf16* __restrict__ fh,
                                                 __bf16* __restrict__ fm,
                                                 __bf16* __restrict__ fl) {
    __shared__ float tile[64][65];
    int b = blockIdx.y, n0 = blockIdx.x * 64, t = threadIdx.x;
    int j = t & 63, c0 = (t >> 6) * 16;
    #pragma unroll
    for (int cc = 0; cc < 16; ++cc)
        tile[c0 + cc][j] = x[((size_t)b * Cn + c0 + cc) * Np + n0 + j];
    __syncthreads();
    int n_loc = t & 63, cq = (t >> 6) * 16;
    bf16x8 vh[2], vm[2], vl[2];
    #pragma unroll
    for (int g = 0; g < 2; ++g)
        #pragma unroll
        for (int u = 0; u < 8; ++u) {
            __bf16 h, m, lo;
            split3(tile[cq + g * 8 + u][n_loc], h, m, lo);
            vh[g][u] = h; vm[g][u] = m; vl[g][u] = lo;
        }
    size_t base = ((size_t)b * Np + n0 + n_loc) * Cn + cq;
    *(bf16x8*)&fh[base] = vh[0]; *(bf16x8*)&fh[base + 8] = vh[1];
    *(bf16x8*)&fm[base] = vm[0]; *(bf16x8*)&fm[base + 8] = vm[1];
    *(bf16x8*)&fl[base] = vl[0]; *(bf16x8*)&fl[base + 8] = vl[1];
}

// ---------------- centroid init (f32 + 3-term bf16 + cnorm) ----------------
__global__ __launch_bounds__(64) void init_cent3_k(const float* __restrict__ x,
                                                   float* __restrict__ cent_f32,
                                                   __bf16* __restrict__ ch_,
                                                   __bf16* __restrict__ cm_,
                                                   __bf16* __restrict__ cl_,
                                                   float* __restrict__ cnorm) {
    int b = blockIdx.y, s = blockIdx.x, c = threadIdx.x;
    int n = s * (Np / Sc);
    float v = x[((size_t)b * Cn + c) * Np + n];
    int o = (b * Sc + s) * Cn + c;
    cent_f32[o] = v;
    __bf16 h, m, lo; split3(v, h, m, lo);
    ch_[o] = h; cm_[o] = m; cl_[o] = lo;
    float sq = v * v;
    #pragma unroll
    for (int off = 32; off >= 1; off >>= 1) sq += __shfl_down(sq, off);
    if (c == 0) cnorm[b * Sc + s] = sq;
}

// ---------------- w2 -> bf16, permuted to [k][o][c] ----------------
__global__ __launch_bounds__(256) void w2prep_k(const float* __restrict__ w2,
                                                __bf16* __restrict__ w2kg) {
    int i = blockIdx.x * 256 + threadIdx.x;   // 36864 total
    int k = i >> 12, rem = i & 4095, o = rem >> 6, c = rem & 63;
    w2kg[i] = (__bf16)w2[o * Dd + c * 9 + k];
}

// ---------------- fused Lloyd iteration: MFMA assign (6-product) + exact fallback + MFMA update ----------------
__global__ __launch_bounds__(256, 2) void kmeans_fused2_k(
        const float* __restrict__ x,
        const __bf16* __restrict__ fh, const __bf16* __restrict__ fm, const __bf16* __restrict__ fl,
        const float* __restrict__ cent_f32,
        const __bf16* __restrict__ ch_, const __bf16* __restrict__ cm_, const __bf16* __restrict__ cl_,
        const float* __restrict__ cnorm,
        int* __restrict__ idxg, float* __restrict__ gpart,
        float* __restrict__ out_idx, int do_update) {
    __shared__ __bf16 Bt_h[64][72];
    __shared__ __bf16 Bt_m[64][72];
    __shared__ __bf16 Bt_l[64][72];
    __shared__ __bf16 A_oh[32][72];
    __shared__ int idx_s[256];
    __shared__ int redint[4][32];
    __shared__ float centf_s[32][64];
    __shared__ float cnorm_s[32];
    int b = blockIdx.y, n0 = blockIdx.x * 256, t = threadIdx.x;
    int w = t >> 6, l = t & 63, arow = l & 15, kg = l >> 4;

    // stage f32 centroids + norms (for exact fallback)
    for (int i = t; i < Sc * Cn; i += 256) ((float*)centf_s)[i] = cent_f32[b * Sc * Cn + i];
    if (t < Sc) cnorm_s[t] = cnorm[b * Sc + t];

    // ---- phase A: scores via 3-term split MFMA (6 products) ----
    bf16x8 cbh[2][2], cbm[2][2], cbl[2][2];
    #pragma unroll
    for (int st = 0; st < 2; ++st)
        #pragma unroll
        for (int kt = 0; kt < 2; ++kt) {
            size_t cb = (size_t)(b * Sc + st * 16 + arow) * Cn + kt * 32 + kg * 8;
            cbh[st][kt] = *(const bf16x8*)&ch_[cb];
            cbm[st][kt] = *(const bf16x8*)&cm_[cb];
            cbl[st][kt] = *(const bf16x8*)&cl_[cb];
        }
    float cn0 = cnorm[b * Sc + arow];
    float cn1 = cnorm[b * Sc + 16 + arow];

    f32x4 dacc[4][2];
    #pragma unroll
    for (int mt = 0; mt < 4; ++mt) {
        dacc[mt][0] = (f32x4){0.f, 0.f, 0.f, 0.f};
        dacc[mt][1] = (f32x4){0.f, 0.f, 0.f, 0.f};
    }
    #pragma unroll
    for (int mt = 0; mt < 4; ++mt) {
        size_t fb = ((size_t)b * Np + n0 + w * 64 + mt * 16 + arow) * Cn;
        bf16x8 ah[2], am2[2], al2[2];
        #pragma unroll
        for (int kt = 0; kt < 2; ++kt) {
            ah[kt]  = *(const bf16x8*)&fh[fb + kt * 32 + kg * 8];
            am2[kt] = *(const bf16x8*)&fm[fb + kt * 32 + kg * 8];
            al2[kt] = *(const bf16x8*)&fl[fb + kt * 32 + kg * 8];
        }
        #pragma unroll
        for (int st = 0; st < 2; ++st)
            #pragma unroll
            for (int kt = 0; kt < 2; ++kt) {
                dacc[mt][st] = __builtin_amdgcn_mfma_f32_16x16x32_bf16(ah[kt],  cbh[st][kt], dacc[mt][st], 0, 0, 0);
                dacc[mt][st] = __builtin_amdgcn_mfma_f32_16x16x32_bf16(ah[kt],  cbm[st][kt], dacc[mt][st], 0, 0, 0);
                dacc[mt][st] = __builtin_amdgcn_mfma_f32_16x16x32_bf16(am2[kt], cbh[st][kt], dacc[mt][st], 0, 0, 0);
                dacc[mt][st] = __builtin_amdgcn_mfma_f32_16x16x32_bf16(ah[kt],  cbl[st][kt], dacc[mt][st], 0, 0, 0);
                dacc[mt][st] = __builtin_amdgcn_mfma_f32_16x16x32_bf16(al2[kt], cbh[st][kt], dacc[mt][st], 0, 0, 0);
                dacc[mt][st] = __builtin_amdgcn_mfma_f32_16x16x32_bf16(am2[kt], cbm[st][kt], dacc[mt][st], 0, 0, 0);
            }
    }
    __syncthreads();   // centf_s staged before fallback may read it

    // argmin + top-2 gap + exact fallback for near-ties
    #pragma unroll
    for (int mt = 0; mt < 4; ++mt)
        #pragma unroll
        for (int r = 0; r < 4; ++r) {
            float dA = cn0 - 2.f * dacc[mt][0][r];
            float dB = cn1 - 2.f * dacc[mt][1][r];
            float d1, d2; int s1;
            if (dB < dA) { d1 = dB; s1 = arow + 16; d2 = dA; }
            else         { d1 = dA; s1 = arow;      d2 = dB; }
            #pragma unroll
            for (int mk = 1; mk < 16; mk <<= 1) {
                float d1o = __shfl_xor(d1, mk);
                int   s1o = __shfl_xor(s1, mk);
                float d2o = __shfl_xor(d2, mk);
                float big = fmaxf(d1, d1o);
                d2 = fminf(fminf(d2, d2o), big);
                if (d1o < d1 || (d1o == d1 && s1o < s1)) { d1 = d1o; s1 = s1o; }
            }
            int pix = w * 64 + mt * 16 + kg * 4 + r;
            bool writer = (arow == 0);
            if (writer) idx_s[pix] = s1;
            bool flag = writer && ((d2 - d1) < 1e-4f * (1.f + fabsf(d1)));
            unsigned long long bal = __ballot(flag);
            while (bal) {
                int src = __ffsll(bal) - 1;
                bal &= bal - 1;
                int fp = w * 64 + mt * 16 + (src >> 4) * 4 + r;
                int n = n0 + fp;
                int s = l & 31, c0 = (l >> 5) * 32;
                float acc2 = 0.f;
                #pragma unroll 8
                for (int c = 0; c < 32; ++c)
                    acc2 = fmaf(x[((size_t)b * Cn + c0 + c) * Np + n], centf_s[s][c0 + c], acc2);
                acc2 += __shfl_xor(acc2, 32);
                float dd = cnorm_s[s] - 2.f * acc2;
                int ss = s;
                #pragma unroll
                for (int mk = 1; mk < 32; mk <<= 1) {
                    float ddo = __shfl_xor(dd, mk);
                    int   sso = __shfl_xor(ss, mk);
                    if (ddo < dd || (ddo == dd && sso < ss)) { dd = ddo; ss = sso; }
                }
                if (l == 0) idx_s[fp] = ss;
            }
        }
    __syncthreads();

    int best = idx_s[t];
    idxg[b * Np + n0 + t] = best;
    if (out_idx) out_idx[b * Np + n0 + t] = (float)best;
    if (!do_update) return;

    // deterministic counts via ballot
    #pragma unroll 4
    for (int s = 0; s < Sc; ++s) {
        unsigned long long bal = __ballot(best == s);
        if (l == 0) redint[w][s] = __popcll(bal);
    }

    // ---- phase B: per-block cluster sums via one-hot MFMA (3-term B) ----
    f32x4 uacc[2];
    uacc[0] = (f32x4){0.f, 0.f, 0.f, 0.f};
    uacc[1] = (f32x4){0.f, 0.f, 0.f, 0.f};
    for (int mc = 0; mc < 4; ++mc) {
        __syncthreads();
        {   // stage Bt chunk [c][64 m] 3-term from x (coalesced channel-major)
            int c = t >> 2, mq = t & 3;
            const float* xp = &x[((size_t)b * Cn + c) * Np + n0 + mc * 64 + mq * 16];
            #pragma unroll
            for (int u = 0; u < 4; ++u) {
                f32x4 v = *(const f32x4*)&xp[u * 4];
                bf16x4 hv, mv, lv;
                #pragma unroll
                for (int e = 0; e < 4; ++e) {
                    __bf16 h, m, lo; split3(v[e], h, m, lo);
                    hv[e] = h; mv[e] = m; lv[e] = lo;
                }
                *(bf16x4*)&Bt_h[c][mq * 16 + u * 4] = hv;
                *(bf16x4*)&Bt_m[c][mq * 16 + u * 4] = mv;
                *(bf16x4*)&Bt_l[c][mq * 16 + u * 4] = lv;
            }
        }
        {   // build one-hot A columns
            int m = t & 63, sq = t >> 6;
            int bm = idx_s[mc * 64 + m];
            #pragma unroll
            for (int u = 0; u < 8; ++u)
                A_oh[sq * 8 + u][m] = (sq * 8 + u == bm) ? (__bf16)1.0f : (__bf16)0.0f;
        }
        __syncthreads();
        #pragma unroll
        for (int kh = 0; kh < 2; ++kh) {
            bf16x8 bh = *(const bf16x8*)&Bt_h[w * 16 + arow][kh * 32 + kg * 8];
            bf16x8 bm2 = *(const bf16x8*)&Bt_m[w * 16 + arow][kh * 32 + kg * 8];
            bf16x8 bl2 = *(const bf16x8*)&Bt_l[w * 16 + arow][kh * 32 + kg * 8];
            #pragma unroll
            for (int smt = 0; smt < 2; ++smt) {
                bf16x8 af = *(const bf16x8*)&A_oh[smt * 16 + arow][kh * 32 + kg * 8];
                uacc[smt] = __builtin_amdgcn_mfma_f32_16x16x32_bf16(af, bh,  uacc[smt], 0, 0, 0);
                uacc[smt] = __builtin_amdgcn_mfma_f32_16x16x32_bf16(af, bm2, uacc[smt], 0, 0, 0);
                uacc[smt] = __builtin_amdgcn_mfma_f32_16x16x32_bf16(af, bl2, uacc[smt], 0, 0, 0);
            }
        }
    }
    float* gp = &gpart[(size_t)(b * KMB + blockIdx.x) * (Sc * 65)];
    #pragma unroll
    for (int smt = 0; smt < 2; ++smt)
        #pragma unroll
        for (int r = 0; r < 4; ++r)
            gp[(smt * 16 + kg * 4 + r) * 65 + w * 16 + arow] = uacc[smt][r];
    if (t < Sc)
        gp[t * 65 + 64] = (float)(redint[0][t] + redint[1][t] + redint[2][t] + redint[3][t]);
}

// ---------------- reduce partials -> new centroids (4-wave parallel) ----------------
__global__ __launch_bounds__(256) void update_reduce3_k(const float* __restrict__ gpart,
                                                        float* __restrict__ cent_f32,
                                                        __bf16* __restrict__ ch_,
                                                        __bf16* __restrict__ cm_,
                                                        __bf16* __restrict__ cl_,
                                                        float* __restrict__ cnorm) {
    __shared__ float psum[4][64];
    __shared__ float pcnt[4];
    int b = blockIdx.y, s = blockIdx.x, t = threadIdx.x;
    int w = t >> 6, c = t & 63;
    float sum = 0.f, cnt = 0.f;
    #pragma unroll 4
    for (int blk = w * 16; blk < w * 16 + 16; ++blk) {
        const float* g = &gpart[(size_t)(b * KMB + blk) * (Sc * 65) + s * 65];
        sum += g[c];
        if (c == 0) cnt += g[64];
    }
    psum[w][c] = sum;
    if (c == 0) pcnt[w] = cnt;
    __syncthreads();
    if (t < 64) {
        float m = psum[0][t] + psum[1][t] + psum[2][t] + psum[3][t];
        float ct = pcnt[0] + pcnt[1] + pcnt[2] + pcnt[3];
        float mean = m / fmaxf(ct, 1.f);
        int o = (b * Sc + s) * Cn + t;
        cent_f32[o] = mean;
        __bf16 h, mm, lo; split3(mean, h, mm, lo);
        ch_[o] = h; cm_[o] = mm; cl_[o] = lo;
        float sq = mean * mean;
        #pragma unroll
        for (int off = 32; off >= 1; off >>= 1) sq += __shfl_down(sq, off);
        if (t == 0) cnorm[b * Sc + s] = sq;
    }
}

// ---------------- cluster patch sums via one-hot MFMA GEMM ----------------
__global__ __launch_bounds__(512) void centp_mfma_k(const float* __restrict__ x,
                                                    const int* __restrict__ idxg,
                                                    float* __restrict__ partialP) {
    __shared__ __bf16 Amat[288 * 56];
    __shared__ __bf16 Bt[64 * 56];
    int b = blockIdx.y, kb = blockIdx.x, t = threadIdx.x;
    int w = t >> 6, l = t & 63;
    int wm = w >> 2, wn = w & 3;
    int arow = l & 15, kg = l >> 4;
    f32x4 acc[9];
    #pragma unroll
    for (int j = 0; j < 9; ++j) acc[j] = (f32x4){0.f, 0.f, 0.f, 0.f};

    int m_base = kb * 512;
    for (int kt = 0; kt < 16; ++kt) {
        int m0 = m_base + kt * 32;
        #pragma unroll
        for (int j = 0; j < 9; ++j) {
            int i = t + 512 * j;
            int row = i >> 4, dc = i & 15;
            *(unsigned*)&Amat[row * 56 + dc * 2] = 0u;
        }
        {
            int c = t >> 3, k0 = (t & 7) * 4;
            f32x4 v = *(const f32x4*)&x[((size_t)b * Cn + c) * Np + m0 + k0];
            bf16x4 bv4;
            bv4[0] = (__bf16)v.x; bv4[1] = (__bf16)v.y;
            bv4[2] = (__bf16)v.z; bv4[3] = (__bf16)v.w;
            *(bf16x4*)&Bt[c * 56 + k0] = bv4;
        }
        __syncthreads();
        if (t < 288) {
            int m = t & 31, k = t >> 5;
            int mg = m0 + m, mh = mg >> 7, mw = mg & 127;
            int dh = k / 3 - 1, dw = k % 3 - 1;
            int nh = mh - dh, nw = mw - dw;
            if (((unsigned)nh < 128u) && ((unsigned)nw < 128u)) {
                int s = idxg[b * Np + (nh << 7) + nw];
                Amat[(s * 9 + k) * 56 + m] = (__bf16)1.0f;
            }
        }
        __syncthreads();
        bf16x8 bfrag = *(const bf16x8*)&Bt[(wn * 16 + arow) * 56 + kg * 8];
        #pragma unroll
        for (int j = 0; j < 9; ++j) {
            int mt = wm * 9 + j;
            bf16x8 afrag = *(const bf16x8*)&Amat[(mt * 16 + arow) * 56 + kg * 8];
            acc[j] = __builtin_amdgcn_mfma_f32_16x16x32_bf16(afrag, bfrag, acc[j], 0, 0, 0);
        }
        __syncthreads();
    }
    float* P = partialP + (size_t)(b * KBLK + kb) * 288 * 64;
    #pragma unroll
    for (int j = 0; j < 9; ++j) {
        int R0 = (wm * 9 + j) * 16 + kg * 4;
        int col = wn * 16 + arow;
        #pragma unroll
        for (int r = 0; r < 4; ++r) P[(size_t)(R0 + r) * 64 + col] = acc[j][r];
    }
}

// ---------------- reduce patch partials + counts -> softmax attention ----------------
__global__ __launch_bounds__(576) void centp_att2_k(const float* __restrict__ partialP,
                                                    const int* __restrict__ idxg,
                                                    const float* __restrict__ kg_w,
                                                    const float* __restrict__ kg_b,
                                                    float* __restrict__ attb) {
    __shared__ float cpm[9][64];
    __shared__ float logit[9];
    __shared__ int   redint[9];
    __shared__ float cnt_sh;
    int b = blockIdx.y, s = blockIdx.x, t = threadIdx.x;
    int k = t >> 6, c = t & 63;

    float sum = 0.f;
    for (int kb = 0; kb < KBLK; ++kb)
        sum += partialP[((size_t)(b * KBLK + kb) * 288 + s * 9 + k) * 64 + c];

    int cloc = 0;
    for (int i = t; i < Np; i += 576) cloc += (idxg[b * Np + i] == s);
    #pragma unroll
    for (int off = 32; off >= 1; off >>= 1) cloc += __shfl_down(cloc, off);
    if ((t & 63) == 0) redint[k] = cloc;
    __syncthreads();
    if (t == 0) {
        int c2 = 0;
        #pragma unroll
        for (int j = 0; j < 9; ++j) c2 += redint[j];
        cnt_sh = fmaxf((float)c2, 1.f);
    }
    __syncthreads();
    cpm[k][c] = sum / cnt_sh;
    __syncthreads();

    float pr = 0.f;
    #pragma unroll
    for (int u = 0; u < 9; ++u)
        pr = fmaf(cpm[u][c], kg_w[k * Dd + c * 9 + u], pr);
    #pragma unroll
    for (int off = 32; off >= 1; off >>= 1) pr += __shfl_down(pr, off);
    if ((t & 63) == 0) logit[k] = pr + kg_b[k];
    __syncthreads();
    if (t == 0) {
        float mx = logit[0];
        #pragma unroll
        for (int jj = 1; jj < 9; ++jj) mx = fmaxf(mx, logit[jj]);
        float e[9], sm = 0.f;
        #pragma unroll
        for (int jj = 0; jj < 9; ++jj) { e[jj] = expf(logit[jj] - mx); sm += e[jj]; }
        #pragma unroll
        for (int jj = 0; jj < 9; ++jj) attb[(b * Sc + s) * 9 + jj] = e[jj] / sm * 9.f;
    }
}

// ---------------- final: 128px x 64out tile; LDS w2 (2 phases); scale-after-MFMA ----------------
__global__ __launch_bounds__(512, 4) void final_out5_k(const float* __restrict__ x,
                                                       const __bf16* __restrict__ fh,
                                                       const int* __restrict__ idxg,
                                                       const float* __restrict__ attb,
                                                       const __bf16* __restrict__ w2kg,
                                                       const float* __restrict__ b2,
                                                       float* __restrict__ out) {
    __shared__ __align__(16) char smem[46080];   // w2l[5][64][72] bf16  /  trans[64][132] f32
    __shared__ float apix_t[9][132];
    __shared__ float b2s[64];
    __bf16 (*w2l)[64][72] = (__bf16 (*)[64][72])smem;
    float (*trans)[132]   = (float (*)[132])smem;

    int b = blockIdx.y, hh = blockIdx.x, n0 = hh * 128, t = threadIdx.x;
    int w = t >> 6, l = t & 63, arow = l & 15, kg = l >> 4;

    if (t < 128) {
        int s = idxg[b * Np + n0 + t];
        const float* ap = attb + (b * Sc + s) * 9;
        #pragma unroll
        for (int k = 0; k < 9; ++k) apix_t[k][t] = ap[k];
    } else if (t < 192) {
        b2s[t - 128] = b2[t - 128];
    }
    // stage w2 k=0..4
    for (int q = t; q < 2560; q += 512) {
        int kk = q >> 9, rem = q & 511, o = rem >> 3, c0 = (rem & 7) * 8;
        *(bf16x8*)&w2l[kk][o][c0] = *(const bf16x8*)&w2kg[(size_t)kk * 4096 + o * 64 + c0];
    }
    __syncthreads();

    int px = w * 16 + arow;        // A-frag row pixel
    f32x4 acc[4];
    #pragma unroll
    for (int nt = 0; nt < 4; ++nt) acc[nt] = (f32x4){0.f, 0.f, 0.f, 0.f};

    #define K_BODY(k, kk)                                                                  \
    {                                                                                      \
        const int dh = (k) / 3 - 1, dw = (k) % 3 - 1;                                      \
        int h2 = hh + dh, wc = px + dw;                                                    \
        bool valid = ((unsigned)h2 < 128u) && ((unsigned)wc < 128u);                       \
        const __bf16* fr = fh + (((size_t)b * Np + (h2 << 7) + wc) << 6);                  \
        bf16x8 av0 = (bf16x8)(__bf16)0.0f, av1 = (bf16x8)(__bf16)0.0f;                     \
        if (valid) {                                                                       \
            av0 = *(const bf16x8*)&fr[kg * 8];                                             \
            av1 = *(const bf16x8*)&fr[32 + kg * 8];                                        \
        }                                                                                  \
        f32x4 a4 = *(const f32x4*)&apix_t[k][w * 16 + kg * 4];                             \
        f32x4 acck[4];                                                                     \
        _Pragma("unroll")                                                                  \
        for (int nt = 0; nt < 4; ++nt) {                                                   \
            bf16x8 bv0 = *(const bf16x8*)&w2l[kk][nt * 16 + arow][kg * 8];                 \
            bf16x8 bv1 = *(const bf16x8*)&w2l[kk][nt * 16 + arow][32 + kg * 8];            \
            acck[nt] = __builtin_amdgcn_mfma_f32_16x16x32_bf16(av0, bv0,                   \
                           (f32x4){0.f, 0.f, 0.f, 0.f}, 0, 0, 0);                          \
            acck[nt] = __builtin_amdgcn_mfma_f32_16x16x32_bf16(av1, bv1, acck[nt], 0, 0, 0);\
        }                                                                                  \
        _Pragma("unroll")                                                                  \
        for (int nt = 0; nt < 4; ++nt)                                                     \
            _Pragma("unroll")                                                              \
            for (int r = 0; r < 4; ++r)                                                    \
                acc[nt][r] = fmaf(a4[r], acck[nt][r], acc[nt][r]);                         \
    }

    K_BODY(0, 0) K_BODY(1, 1) K_BODY(2, 2) K_BODY(3, 3) K_BODY(4, 4)
    __syncthreads();
    // stage w2 k=5..8
    for (int q = t; q < 2048; q += 512) {
        int kk = q >> 9, rem = q & 511, o = rem >> 3, c0 = (rem & 7) * 8;
        *(bf16x8*)&w2l[kk][o][c0] = *(const bf16x8*)&w2kg[(size_t)(kk + 5) * 4096 + o * 64 + c0];
    }
    __syncthreads();
    K_BODY(5, 0) K_BODY(6, 1) K_BODY(7, 2) K_BODY(8, 3)
    #undef K_BODY

    __syncthreads();   // all LDS reads done before trans overwrite
    #pragma unroll
    for (int nt = 0; nt < 4; ++nt)
        #pragma unroll
        for (int r = 0; r < 4; ++r)
            trans[nt * 16 + arow][w * 16 + kg * 4 + r] = acc[nt][r];
    __syncthreads();
    for (int i = t; i < 8192; i += 512) {
        int o = i >> 7, p2 = i & 127;
        size_t gi = ((size_t)b * On + o) * Np + n0 + p2;
        out[gi] = x[gi] + trans[o][p2] + b2s[o];
    }
}

extern "C" void kernel_launch(void* const* d_in, const int* in_sizes, int n_in,
                              void* d_out, int out_size, void* d_ws, size_t ws_size,
                              hipStream_t stream) {
    (void)in_sizes; (void)n_in; (void)out_size; (void)ws_size;
    const float* x    = (const float*)d_in[0];
    const float* kg_w = (const float*)d_in[5];
    const float* kg_b = (const float*)d_in[6];
    const float* w2   = (const float*)d_in[7];
    const float* b2   = (const float*)d_in[8];
    float* out = (float*)d_out;

    char* p = (char*)d_ws;
    __bf16* fh      = (__bf16*)p; p += (size_t)Bn * Np * Cn * 2;     // 16.78 MB
    __bf16* fm      = (__bf16*)p; p += (size_t)Bn * Np * Cn * 2;     // 16.78 MB
    __bf16* fl      = (__bf16*)p; p += (size_t)Bn * Np * Cn * 2;     // 16.78 MB
    float*  cent_f32= (float*)p;  p += (size_t)Bn * Sc * Cn * 4;
    __bf16* ch_     = (__bf16*)p; p += (size_t)Bn * Sc * Cn * 2;
    __bf16* cm_     = (__bf16*)p; p += (size_t)Bn * Sc * Cn * 2;
    __bf16* cl_     = (__bf16*)p; p += (size_t)Bn * Sc * Cn * 2;
    float*  cnorm   = (float*)p;  p += (size_t)Bn * Sc * 4;
    int*    idxg    = (int*)p;    p += (size_t)Bn * Np * 4;
    float*  gpart   = (float*)p;  p += (size_t)Bn * KMB * Sc * 65 * 4;      // 4.26 MB
    float*  partialP= (float*)p;  p += (size_t)Bn * KBLK * 288 * 64 * 4;    // 18.87 MB
    float*  attb    = (float*)p;  p += (size_t)Bn * Sc * 9 * 4;
    __bf16* w2kg    = (__bf16*)p; p += (size_t)9 * On * Cn * 2;

    featbf3_k<<<dim3(Np / 64, Bn), 256, 0, stream>>>(x, fh, fm, fl);
    init_cent3_k<<<dim3(Sc, Bn), 64, 0, stream>>>(x, cent_f32, ch_, cm_, cl_, cnorm);
    w2prep_k<<<(On * Dd) / 256, 256, 0, stream>>>(w2, w2kg);

    for (int it = 0; it < KM_ITERS; ++it) {
        kmeans_fused2_k<<<dim3(KMB, Bn), 256, 0, stream>>>(
            x, fh, fm, fl, cent_f32, ch_, cm_, cl_, cnorm, idxg, gpart, nullptr, 1);
        update_reduce3_k<<<dim3(Sc, Bn), 256, 0, stream>>>(gpart, cent_f32, ch_, cm_, cl_, cnorm);
    }
    // final assignment (writes idx int + float output chunk)
    kmeans_fused2_k<<<dim3(KMB, Bn), 256, 0, stream>>>(
        x, fh, fm, fl, cent_f32, ch_, cm_, cl_, cnorm, idxg, gpart,
        out + (size_t)Bn * On * Np, 0);

    centp_mfma_k<<<dim3(KBLK, Bn), 512, 0, stream>>>(x, idxg, partialP);
    centp_att2_k<<<dim3(Sc, Bn), 576, 0, stream>>>(partialP, idxg, kg_w, kg_b, attb);

    final_out5_k<<<dim3(128, Bn), 512, 0, stream>>>(x, fh, idxg, attb, w2kg, b2, out);
}